// Round 9
// baseline (165.669 us; speedup 1.0000x reference)
//
#include <hip/hip_runtime.h>
#include <hip/hip_bf16.h>

#define NROW 8192
#define NDIM 256
#define INV_T (1.0f / 0.07f)
#define K_BOT 819      // first selected descending rank
#define K_TOP 4095     // one past last selected rank
#define N_SEL 3276
#define N_UNSEL 4916   // 8192 - N_SEL (includes diagonal at -10)
#define NBIN 512
#define CAPC 448

typedef unsigned int u32;
typedef unsigned short u16;
typedef short s16;
typedef unsigned long long u64;
typedef __bf16 bf16_t;
typedef s16 s16x8 __attribute__((ext_vector_type(8)));
typedef float f32x4 __attribute__((ext_vector_type(4)));

__device__ __forceinline__ u16 bfbits(float f) {
    return __builtin_bit_cast(u16, (bf16_t)f);   // RNE f32->bf16, raw bits
}
// order-preserving bf16-bits -> u16 key (bigger float <=> bigger key)
__device__ __forceinline__ u16 map16(u16 b) {
    return (b & 0x8000u) ? (u16)~b : (u16)(b | 0x8000u);
}
__device__ __forceinline__ float unmap16(u32 m) {
    u16 b = (m & 0x8000u) ? (u16)(m & 0x7FFFu) : (u16)~(u16)m;
    return __uint_as_float(((u32)b) << 16);
}
// monotone linear value->bin map; sentinel key 0 -> NaN -> cvt 0 -> bin 0
__device__ __forceinline__ int binOf(u32 m) {
    float f = unmap16(m);
    int i = (int)((f + 90.0f) * ((float)NBIN / 180.0f));
    return min(max(i, 0), NBIN - 1);
}

__device__ __forceinline__ void gload16(const void* g, void* l) {
    __builtin_amdgcn_global_load_lds(
        (const __attribute__((address_space(1))) u32*)g,
        (__attribute__((address_space(3))) u32*)l, 16, 0, 0);
}

// ---------------- fp32 -> bf16 (both inputs, one launch) ----------------
__global__ __launch_bounds__(256) void cvt_bf16(const float* __restrict__ in0,
                                                const float* __restrict__ in1,
                                                u16* __restrict__ out0,
                                                u16* __restrict__ out1) {
    int b = blockIdx.x;
    const float* in = (b < 2048) ? in0 : in1;
    u16* out = (b < 2048) ? out0 : out1;
    int i = ((b & 2047) * 256 + threadIdx.x) * 4;
    float4 v = *(const float4*)(in + i);
    ushort4 o;
    o.x = bfbits(v.x); o.y = bfbits(v.y); o.z = bfbits(v.z); o.w = bfbits(v.w);
    *(ushort4*)(out + i) = o;
}

// ---------------- GEMM: keys = map16(bf16(Q @ K^T)) ----------------
__global__ __launch_bounds__(256) void gemm_keys(const u16* __restrict__ Qb,
                                                 const u16* __restrict__ Kb,
                                                 u16* __restrict__ Cp) {
    constexpr int BK = 64;
    __shared__ __align__(16) char smem[128 * 132 * 2];
    u16* sA = (u16*)smem;
    u16* sB = (u16*)(smem + 128 * BK * 2);
    u16* sC = (u16*)smem;

    const int tid  = threadIdx.x;
    const int lane = tid & 63;
    const int wid  = tid >> 6;
    const int wr = wid >> 1, wc = wid & 1;

    // XCD-aware bijective swizzle (4096 blocks, 8 XCDs -> 512-block chunks)
    const u32 bid = blockIdx.y * 64 + blockIdx.x;
    const u32 swz = (bid & 7u) * 512u + (bid >> 3);
    const int bm = (int)(swz >> 6) * 128;
    const int bn = (int)(swz & 63u) * 128;

    const int kg = lane >> 4;
    const int fr = lane & 15;
    const int srr = lane >> 3;
    const int srj = (lane & 7) ^ srr;

    f32x4 acc[4][4] = {};

    for (int k0 = 0; k0 < NDIM; k0 += BK) {
        __syncthreads();
#pragma unroll
        for (int s = 0; s < 4; ++s) {
            int seg = wid * 4 + s;
            int row = seg * 8 + srr;
            gload16(Qb + (size_t)(bm + row) * NDIM + k0 + srj * 8, &sA[seg * 512]);
            gload16(Kb + (size_t)(bn + row) * NDIM + k0 + srj * 8, &sB[seg * 512]);
        }
        __syncthreads();

#pragma unroll
        for (int kk = 0; kk < 2; ++kk) {
            s16x8 af[4], bfv[4];
#pragma unroll
            for (int m = 0; m < 4; ++m) {
                int row = wr * 64 + m * 16 + fr;
                int jp = (kk * 4 + kg) ^ (fr & 7);
                af[m] = *(const s16x8*)(&sA[row * BK + jp * 8]);
            }
#pragma unroll
            for (int n = 0; n < 4; ++n) {
                int row = wc * 64 + n * 16 + fr;
                int jp = (kk * 4 + kg) ^ (fr & 7);
                bfv[n] = *(const s16x8*)(&sB[row * BK + jp * 8]);
            }
#pragma unroll
            for (int m = 0; m < 4; ++m)
#pragma unroll
                for (int n = 0; n < 4; ++n)
                    acc[m][n] = __builtin_amdgcn_mfma_f32_16x16x32_bf16(
                        af[m], bfv[n], acc[m][n], 0, 0, 0);
        }
    }

    __syncthreads();
#pragma unroll
    for (int m = 0; m < 4; ++m)
#pragma unroll
        for (int n = 0; n < 4; ++n)
#pragma unroll
            for (int jj = 0; jj < 4; ++jj) {
                int r = wr * 64 + m * 16 + kg * 4 + jj;
                int c = wc * 64 + n * 16 + fr;
                sC[r * 132 + c] = map16(bfbits(acc[m][n][jj]));
            }
    __syncthreads();
    if (bm == bn) {
        if (tid < 128) sC[tid * 132 + tid] = 0;   // diagonal sentinel (unique min)
        __syncthreads();
    }
#pragma unroll
    for (int it = 0; it < 8; ++it) {
        int c = it * 256 + tid;
        int row = c >> 4, col8 = (c & 15) * 8;
        *(uint4*)(&Cp[(size_t)(bm + row) * NROW + bn + col8]) =
            *(const uint4*)(&sC[row * 132 + col8]);
    }
}

// ---------------- wave helpers ----------------
__device__ __forceinline__ u32 wave_sum_u32(u32 x) {
#pragma unroll
    for (int o = 32; o; o >>= 1) x += __shfl_down(x, o);
    return __shfl(x, 0);
}

// exact u16-bisect over a compact LDS list: value at descending rank `rank`
__device__ u32 bisect_list(const u16* lst, u32 n, u32 rank, int lane) {
    const u32 nE = (n + 63) >> 6;          // wave-uniform
    u32 lo = 0, hi = 65535;
    while (lo < hi) {
        u32 mid = (lo + hi) >> 1;
        u32 c = 0;
        for (u32 i = 0; i < nE; ++i) {
            u32 idx = (u32)lane + i * 64;
            u32 k = (idx < n) ? (u32)lst[idx] : 0u;
            c += (u32)__popcll(__ballot(k > mid));
        }
        if (c <= rank) hi = mid; else lo = mid + 1;
    }
    return lo;
}

__device__ void count_list(const u16* lst, u32 n, u32 x, int lane,
                           u32* gt, u32* eq) {
    const u32 nE = (n + 63) >> 6;
    u32 g = 0, e = 0;
    for (u32 i = 0; i < nE; ++i) {
        u32 idx = (u32)lane + i * 64;
        bool v = idx < n;
        u32 k = v ? (u32)lst[idx] : 0u;
        g += (u32)__popcll(__ballot(v && k > x));
        e += (u32)__popcll(__ballot(v && k == x));
    }
    *gt = g; *eq = e;
}

__device__ float sumwin_list(const u16* lst, u32 n, u32 ua, u32 ub,
                             float m_, int lane) {
    const u32 nE = (n + 63) >> 6;
    float s = 0.f;
    for (u32 i = 0; i < nE; ++i) {
        u32 idx = (u32)lane + i * 64;
        if (idx < n) {
            u32 k = lst[idx];
            if (k > ub && k < ua) s += __expf(unmap16(k) * INV_T - m_);
        }
    }
    return s;   // per-lane partial
}

// full-row bisect via global re-sweeps (pathological fallback only)
__device__ u32 bisect_row(const uint4* rp, u32 rank, int lane) {
    u32 lo = 0, hi = 65535;
    while (lo < hi) {
        u32 mid = (lo + hi) >> 1;
        u32 pc = 0;
        for (int i = 0; i < 16; ++i) {
            uint4 v = rp[i * 64 + lane];
            pc += (u32)((v.x & 0xFFFFu) > mid) + (u32)((v.x >> 16) > mid)
                + (u32)((v.y & 0xFFFFu) > mid) + (u32)((v.y >> 16) > mid)
                + (u32)((v.z & 0xFFFFu) > mid) + (u32)((v.z >> 16) > mid)
                + (u32)((v.w & 0xFFFFu) > mid) + (u32)((v.w >> 16) > mid);
        }
        u32 c = wave_sum_u32(pc);
        if (c <= rank) hi = mid; else lo = mid + 1;
    }
    return lo;
}

// ---------------- per-row rank select + LSE: 1 wave/row, 0 barriers --------
__global__ __launch_bounds__(256, 4) void rank_lse(const u16* __restrict__ Cp,
                                                   const float* __restrict__ fq,
                                                   const float* __restrict__ fk,
                                                   float* __restrict__ loss) {
    __shared__ u32 hist_s[4][NBIN];        // 8 KB (per-wave private)
    __shared__ u16 cand_s[4][2 * CAPC];    // 7 KB (per-wave A|B lists)
    __shared__ u32 cnt_s[4][2];

    const int t = threadIdx.x;
    const int w = t >> 6;
    const int lane = t & 63;
    const int row = blockIdx.x * 4 + w;

    u32* hist  = hist_s[w];
    u16* candA = cand_s[w];
    u16* candB = cand_s[w] + CAPC;
    u32* cnt   = cnt_s[w];

    const uint4* rp = (const uint4*)(Cp + (size_t)row * NROW);

    // zero hist + counters (wave-private; DS pipe is in-order per wave)
    {
        const uint4 z = make_uint4(0, 0, 0, 0);
        *(uint4*)&hist[lane * 8]     = z;
        *(uint4*)&hist[lane * 8 + 4] = z;
        if (lane < 2) cnt[lane] = 0;
    }

    // exact fp32 l_pos
    float lp;
    {
        float4 q4 = *(const float4*)(fq + (size_t)row * NDIM + lane * 4);
        float4 k4 = *(const float4*)(fk + (size_t)row * NDIM + lane * 4);
        float p = q4.x * k4.x + q4.y * k4.y + q4.z * k4.z + q4.w * k4.w;
#pragma unroll
        for (int o = 32; o; o >>= 1) p += __shfl_down(p, o);
        lp = __shfl(p, 0);
    }

    // ---- pass 1: linear-bin histogram, 4-deep pipelined loads ----
    {
        uint4 va[4], vb[4];
        auto PROC1 = [&](const uint4* v) {
#pragma unroll
            for (int i = 0; i < 4; ++i) {
                u32 ks[8] = { v[i].x & 0xFFFFu, v[i].x >> 16,
                              v[i].y & 0xFFFFu, v[i].y >> 16,
                              v[i].z & 0xFFFFu, v[i].z >> 16,
                              v[i].w & 0xFFFFu, v[i].w >> 16 };
#pragma unroll
                for (int q = 0; q < 8; ++q)
                    atomicAdd(&hist[binOf(ks[q])], 1u);
            }
        };
#pragma unroll
        for (int i = 0; i < 4; ++i) va[i] = rp[(0 + i) * 64 + lane];
#pragma unroll
        for (int i = 0; i < 4; ++i) vb[i] = rp[(4 + i) * 64 + lane];
        PROC1(va);
#pragma unroll
        for (int i = 0; i < 4; ++i) va[i] = rp[(8 + i) * 64 + lane];
        PROC1(vb);
#pragma unroll
        for (int i = 0; i < 4; ++i) vb[i] = rp[(12 + i) * 64 + lane];
        PROC1(va);
        PROC1(vb);
    }

    // ---- wave-local suffix scan (8 bins/lane); locate boundary bins ----
    u32 h[8], Wa[8];
    {
        uint4 h0 = *(const uint4*)&hist[lane * 8];
        uint4 h1 = *(const uint4*)&hist[lane * 8 + 4];
        h[0] = h0.x; h[1] = h0.y; h[2] = h0.z; h[3] = h0.w;
        h[4] = h1.x; h[5] = h1.y; h[6] = h1.z; h[7] = h1.w;
    }
    Wa[7] = 0;
#pragma unroll
    for (int j = 6; j >= 0; --j) Wa[j] = Wa[j + 1] + h[j + 1];
    u32 P = Wa[0] + h[0];
    u32 s = P;
#pragma unroll
    for (int o = 1; o < 64; o <<= 1) {
        u32 vv = __shfl_down(s, o);
        if (lane + o < 64) s += vv;
    }
    const u32 Tex = s - P;     // keys in bins owned by higher lanes

    u32 fA = 0, pkA = 0, fB = 0, pkB = 0;
#pragma unroll
    for (int j = 0; j < 8; ++j) {
        u32 T = Tex + Wa[j];          // keys in bins strictly above this bin
        u32 e = T + h[j];
        if ((u32)K_BOT >= T && (u32)K_BOT < e)
            { fA = 1; pkA = ((u32)(lane * 8 + j) << 13) | ((u32)K_BOT - T); }
        if ((u32)(K_TOP - 1) >= T && (u32)(K_TOP - 1) < e)
            { fB = 1; pkB = ((u32)(lane * 8 + j) << 13) | ((u32)(K_TOP - 1) - T); }
    }
    {
        u64 mA = __ballot(fA != 0);
        pkA = __shfl(pkA, __ffsll((unsigned long long)mA) - 1);
        u64 mB = __ballot(fB != 0);
        pkB = __shfl(pkB, __ffsll((unsigned long long)mB) - 1);
    }
    const u32 binA = pkA >> 13, remA = pkA & 8191u;
    const u32 binB = pkB >> 13, remB = pkB & 8191u;
    const u32 TA = (u32)K_BOT - remA;
    const u32 TB = (u32)(K_TOP - 1) - remB;
    const u32 hA = hist[binA];
    const u32 hB = hist[binB];
    const bool same = (binA == binB);

    // ---- u16 key-space edges of binA / binB (exact preimage of binOf) ----
    // lane 0: kLo(binA), lane 1: kLo(binA+1), lane 2: kLo(binB), lane 3: kLo(binB+1)
    u32 kALo, kAHip1, kBLo, kBHip1;
    {
        const u32 tsel = (u32)(lane & 3);
        const u32 btgt = (tsel == 0) ? binA : (tsel == 1) ? binA + 1
                       : (tsel == 2) ? binB : binB + 1;
        u32 lo = 0, hi = 65536;
#pragma unroll 1
        for (int it = 0; it < 17; ++it) {
            if (lo < hi) {
                u32 mid = (lo + hi) >> 1;
                if ((u32)binOf(mid) >= btgt) hi = mid; else lo = mid + 1;
            }
        }
        kALo   = __shfl(lo, 0);
        kAHip1 = __shfl(lo, 1);
        kBLo   = __shfl(lo, 2);
        kBHip1 = __shfl(lo, 3);
    }

    u32 ua, ub, Ga, Ea, Gb;
    float m_, smLane;

    if (hA <= CAPC && hB <= CAPC) {
        // ---- fast path: pass 2 = integer-compare classify, pipelined ----
        const float aUp = (float)(binA + 1) * (180.0f / (float)NBIN) - 90.0f;
        m_ = fmaxf(fmaxf(lp, aUp), -10.0f) * INV_T;   // >= true window max
        float sm = 0.f;
        {
            uint4 va[4], vb[4];
            auto PROC2 = [&](const uint4* v) {
#pragma unroll
                for (int i = 0; i < 4; ++i) {
                    u32 ks[8] = { v[i].x & 0xFFFFu, v[i].x >> 16,
                                  v[i].y & 0xFFFFu, v[i].y >> 16,
                                  v[i].z & 0xFFFFu, v[i].z >> 16,
                                  v[i].w & 0xFFFFu, v[i].w >> 16 };
#pragma unroll
                    for (int q = 0; q < 8; ++q) {
                        u32 key = ks[q];
                        if (key >= kALo && key < kAHip1) {
                            u32 ix = atomicAdd(&cnt[0], 1u);
                            candA[ix] = (u16)key;
                        } else if (key >= kBLo && key < kBHip1) {
                            u32 ix = atomicAdd(&cnt[1], 1u);
                            candB[ix] = (u16)key;
                        } else if (key >= kBHip1 && key < kALo) {
                            sm += __expf(unmap16(key) * INV_T - m_);
                        }
                    }
                }
            };
#pragma unroll
            for (int i = 0; i < 4; ++i) va[i] = rp[(0 + i) * 64 + lane];
#pragma unroll
            for (int i = 0; i < 4; ++i) vb[i] = rp[(4 + i) * 64 + lane];
            PROC2(va);
#pragma unroll
            for (int i = 0; i < 4; ++i) va[i] = rp[(8 + i) * 64 + lane];
            PROC2(vb);
#pragma unroll
            for (int i = 0; i < 4; ++i) vb[i] = rp[(12 + i) * 64 + lane];
            PROC2(va);
            PROC2(vb);
        }
        const u32 nA = hA;
        const u32 nB = same ? hA : hB;
        const u16* lB = same ? candA : candB;
        ua = bisect_list(candA, nA, remA, lane);
        ub = bisect_list(lB, nB, remB, lane);
        u32 gA, eA, gB, eB;
        count_list(candA, nA, ua, lane, &gA, &eA);
        count_list(lB, nB, ub, lane, &gB, &eB);
        Ga = TA + gA; Ea = eA; Gb = TB + gB;
        sm += sumwin_list(candA, nA, ua, ub, m_, lane);
        if (!same) sm += sumwin_list(candB, nB, ua, ub, m_, lane);
        smLane = sm;
    } else {
        // ---- fallback: exact full-row bisect (pathological data only) ----
        ua = bisect_row(rp, (u32)K_BOT, lane);
        ub = bisect_row(rp, (u32)(K_TOP - 1), lane);
        m_ = fmaxf(fmaxf(lp, unmap16(ua)), -10.0f) * INV_T;
        u32 cga = 0, cea = 0, cgb = 0;
        float sm = 0.f;
        for (int i = 0; i < 16; ++i) {
            uint4 v = rp[i * 64 + lane];
            u32 ks[8] = { v.x & 0xFFFFu, v.x >> 16, v.y & 0xFFFFu, v.y >> 16,
                          v.z & 0xFFFFu, v.z >> 16, v.w & 0xFFFFu, v.w >> 16 };
#pragma unroll
            for (int q = 0; q < 8; ++q) {
                u32 u = ks[q];
                cga += (u > ua); cea += (u == ua); cgb += (u > ub);
                if (u > ub && u < ua) sm += __expf(unmap16(u) * INV_T - m_);
            }
        }
        Ga = wave_sum_u32(cga); Ea = wave_sum_u32(cea); Gb = wave_sum_u32(cgb);
        smLane = sm;
    }

    // wave-reduce the exp partials
    float smT = smLane;
#pragma unroll
    for (int o = 32; o; o >>= 1) smT += __shfl_down(smT, o);

    if (lane == 0) {
        float a = unmap16(ua), bv = unmap16(ub);
        float expA = __expf(a * INV_T - m_);
        float tot;
        if (ua == ub) {
            tot = (float)N_SEL * expA;
        } else {
            float expB = __expf(bv * INV_T - m_);
            tot = smT + (float)(int)(Ga + Ea - (u32)K_BOT) * expA
                      + (float)(int)((u32)K_TOP - Gb) * expB;
        }
        tot += __expf(lp * INV_T - m_) + (float)N_UNSEL * __expf(-10.0f * INV_T - m_);
        loss[row] = m_ + __logf(tot) - lp * INV_T;
    }
}

// ---------------- host ----------------
extern "C" void kernel_launch(void* const* d_in, const int* in_sizes, int n_in,
                              void* d_out, int out_size, void* d_ws, size_t ws_size,
                              hipStream_t stream) {
    const float* fq = (const float*)d_in[0];
    const float* fk = (const float*)d_in[1];
    float* out = (float*)d_out;

    char* ws = (char*)d_ws;
    u16* keys = (u16*)ws;                                  // 128 MiB
    u16* qb = (u16*)(ws + (size_t)NROW * NROW * 2);        // 4 MiB
    u16* kb = qb + (size_t)NROW * NDIM;                    // 4 MiB

    cvt_bf16<<<4096, 256, 0, stream>>>(fq, fk, qb, kb);
    gemm_keys<<<dim3(NROW / 128, NROW / 128), 256, 0, stream>>>(qb, kb, keys);
    rank_lse<<<NROW / 4, 256, 0, stream>>>(keys, fq, fk, out);
}

// Round 10
// 157.870 us; speedup vs baseline: 1.0494x; 1.0494x over previous
//
#include <hip/hip_runtime.h>
#include <hip/hip_bf16.h>

#define NROW 8192
#define NDIM 256
#define INV_T (1.0f / 0.07f)
#define K_BOT 819      // first selected descending rank
#define K_TOP 4095     // one past last selected rank
#define N_SEL 3276
#define N_UNSEL 4916   // 8192 - N_SEL (includes diagonal at -10)
#define NBIN 512
#define CAPC 448

typedef unsigned int u32;
typedef unsigned short u16;
typedef short s16;
typedef unsigned long long u64;
typedef __bf16 bf16_t;
typedef s16 s16x8 __attribute__((ext_vector_type(8)));
typedef float f32x4 __attribute__((ext_vector_type(4)));

__device__ __forceinline__ u16 bfbits(float f) {
    return __builtin_bit_cast(u16, (bf16_t)f);   // RNE f32->bf16, raw bits
}
// order-preserving bf16-bits -> u16 key (bigger float <=> bigger key)
__device__ __forceinline__ u16 map16(u16 b) {
    return (b & 0x8000u) ? (u16)~b : (u16)(b | 0x8000u);
}
__device__ __forceinline__ float unmap16(u32 m) {
    u16 b = (m & 0x8000u) ? (u16)(m & 0x7FFFu) : (u16)~(u16)m;
    return __uint_as_float(((u32)b) << 16);
}
// monotone linear value->bin map; sentinel key 0 -> NaN -> cvt 0 -> bin 0
__device__ __forceinline__ int binOf(u32 m) {
    float f = unmap16(m);
    int i = (int)((f + 90.0f) * ((float)NBIN / 180.0f));
    return min(max(i, 0), NBIN - 1);
}

__device__ __forceinline__ void gload16(const void* g, void* l) {
    __builtin_amdgcn_global_load_lds(
        (const __attribute__((address_space(1))) u32*)g,
        (__attribute__((address_space(3))) u32*)l, 16, 0, 0);
}

// ---------------- fp32 -> bf16 (both inputs, one launch) ----------------
__global__ __launch_bounds__(256) void cvt_bf16(const float* __restrict__ in0,
                                                const float* __restrict__ in1,
                                                u16* __restrict__ out0,
                                                u16* __restrict__ out1) {
    int b = blockIdx.x;
    const float* in = (b < 2048) ? in0 : in1;
    u16* out = (b < 2048) ? out0 : out1;
    int i = ((b & 2047) * 256 + threadIdx.x) * 4;
    float4 v = *(const float4*)(in + i);
    ushort4 o;
    o.x = bfbits(v.x); o.y = bfbits(v.y); o.z = bfbits(v.z); o.w = bfbits(v.w);
    *(ushort4*)(out + i) = o;
}

// ---------------- GEMM: keys = map16(bf16(Q @ K^T)) ----------------
__global__ __launch_bounds__(256) void gemm_keys(const u16* __restrict__ Qb,
                                                 const u16* __restrict__ Kb,
                                                 u16* __restrict__ Cp) {
    constexpr int BK = 64;
    __shared__ __align__(16) char smem[128 * 132 * 2];
    u16* sA = (u16*)smem;
    u16* sB = (u16*)(smem + 128 * BK * 2);
    u16* sC = (u16*)smem;

    const int tid  = threadIdx.x;
    const int lane = tid & 63;
    const int wid  = tid >> 6;
    const int wr = wid >> 1, wc = wid & 1;

    // XCD-aware bijective swizzle (4096 blocks, 8 XCDs -> 512-block chunks)
    const u32 bid = blockIdx.y * 64 + blockIdx.x;
    const u32 swz = (bid & 7u) * 512u + (bid >> 3);
    const int bm = (int)(swz >> 6) * 128;
    const int bn = (int)(swz & 63u) * 128;

    const int kg = lane >> 4;
    const int fr = lane & 15;
    const int srr = lane >> 3;
    const int srj = (lane & 7) ^ srr;

    f32x4 acc[4][4] = {};

    for (int k0 = 0; k0 < NDIM; k0 += BK) {
        __syncthreads();
#pragma unroll
        for (int s = 0; s < 4; ++s) {
            int seg = wid * 4 + s;
            int row = seg * 8 + srr;
            gload16(Qb + (size_t)(bm + row) * NDIM + k0 + srj * 8, &sA[seg * 512]);
            gload16(Kb + (size_t)(bn + row) * NDIM + k0 + srj * 8, &sB[seg * 512]);
        }
        __syncthreads();

#pragma unroll
        for (int kk = 0; kk < 2; ++kk) {
            s16x8 af[4], bfv[4];
#pragma unroll
            for (int m = 0; m < 4; ++m) {
                int row = wr * 64 + m * 16 + fr;
                int jp = (kk * 4 + kg) ^ (fr & 7);
                af[m] = *(const s16x8*)(&sA[row * BK + jp * 8]);
            }
#pragma unroll
            for (int n = 0; n < 4; ++n) {
                int row = wc * 64 + n * 16 + fr;
                int jp = (kk * 4 + kg) ^ (fr & 7);
                bfv[n] = *(const s16x8*)(&sB[row * BK + jp * 8]);
            }
#pragma unroll
            for (int m = 0; m < 4; ++m)
#pragma unroll
                for (int n = 0; n < 4; ++n)
                    acc[m][n] = __builtin_amdgcn_mfma_f32_16x16x32_bf16(
                        af[m], bfv[n], acc[m][n], 0, 0, 0);
        }
    }

    __syncthreads();
#pragma unroll
    for (int m = 0; m < 4; ++m)
#pragma unroll
        for (int n = 0; n < 4; ++n)
#pragma unroll
            for (int jj = 0; jj < 4; ++jj) {
                int r = wr * 64 + m * 16 + kg * 4 + jj;
                int c = wc * 64 + n * 16 + fr;
                sC[r * 132 + c] = map16(bfbits(acc[m][n][jj]));
            }
    __syncthreads();
    if (bm == bn) {
        if (tid < 128) sC[tid * 132 + tid] = 0;   // diagonal sentinel (unique min)
        __syncthreads();
    }
#pragma unroll
    for (int it = 0; it < 8; ++it) {
        int c = it * 256 + tid;
        int row = c >> 4, col8 = (c & 15) * 8;
        *(uint4*)(&Cp[(size_t)(bm + row) * NROW + bn + col8]) =
            *(const uint4*)(&sC[row * 132 + col8]);
    }
}

// ---------------- wave helpers ----------------
__device__ __forceinline__ u32 wave_sum_u32(u32 x) {
#pragma unroll
    for (int o = 32; o; o >>= 1) x += __shfl_down(x, o);
    return __shfl(x, 0);
}

// exact u16-bisect over a compact LDS list: value at descending rank `rank`
__device__ u32 bisect_list(const u16* lst, u32 n, u32 rank, int lane) {
    const u32 nE = (n + 63) >> 6;          // wave-uniform
    u32 lo = 0, hi = 65535;
    while (lo < hi) {
        u32 mid = (lo + hi) >> 1;
        u32 c = 0;
        for (u32 i = 0; i < nE; ++i) {
            u32 idx = (u32)lane + i * 64;
            u32 k = (idx < n) ? (u32)lst[idx] : 0u;
            c += (u32)__popcll(__ballot(k > mid));
        }
        if (c <= rank) hi = mid; else lo = mid + 1;
    }
    return lo;
}

__device__ void count_list(const u16* lst, u32 n, u32 x, int lane,
                           u32* gt, u32* eq) {
    const u32 nE = (n + 63) >> 6;
    u32 g = 0, e = 0;
    for (u32 i = 0; i < nE; ++i) {
        u32 idx = (u32)lane + i * 64;
        bool v = idx < n;
        u32 k = v ? (u32)lst[idx] : 0u;
        g += (u32)__popcll(__ballot(v && k > x));
        e += (u32)__popcll(__ballot(v && k == x));
    }
    *gt = g; *eq = e;
}

__device__ float sumwin_list(const u16* lst, u32 n, u32 ua, u32 ub,
                             float m_, int lane) {
    const u32 nE = (n + 63) >> 6;
    float s = 0.f;
    for (u32 i = 0; i < nE; ++i) {
        u32 idx = (u32)lane + i * 64;
        if (idx < n) {
            u32 k = lst[idx];
            if (k > ub && k < ua) s += __expf(unmap16(k) * INV_T - m_);
        }
    }
    return s;   // per-lane partial
}

// full-row bisect via global re-sweeps (pathological fallback only)
__device__ u32 bisect_row(const uint4* rp, u32 rank, int lane) {
    u32 lo = 0, hi = 65535;
    while (lo < hi) {
        u32 mid = (lo + hi) >> 1;
        u32 pc = 0;
        for (int i = 0; i < 16; ++i) {
            uint4 v = rp[i * 64 + lane];
            pc += (u32)((v.x & 0xFFFFu) > mid) + (u32)((v.x >> 16) > mid)
                + (u32)((v.y & 0xFFFFu) > mid) + (u32)((v.y >> 16) > mid)
                + (u32)((v.z & 0xFFFFu) > mid) + (u32)((v.z >> 16) > mid)
                + (u32)((v.w & 0xFFFFu) > mid) + (u32)((v.w >> 16) > mid);
        }
        u32 c = wave_sum_u32(pc);
        if (c <= rank) hi = mid; else lo = mid + 1;
    }
    return lo;
}

// ---------------- per-row rank select + LSE: 1 wave/row, 0 barriers --------
__global__ __launch_bounds__(256, 8) void rank_lse(const u16* __restrict__ Cp,
                                                   const float* __restrict__ fq,
                                                   const float* __restrict__ fk,
                                                   float* __restrict__ loss) {
    __shared__ u32 hist_s[4][NBIN];        // 8 KB (per-wave private)
    __shared__ u16 cand_s[4][2 * CAPC];    // 7 KB (per-wave A|B lists)
    __shared__ u32 cnt_s[4][2];

    const int t = threadIdx.x;
    const int w = t >> 6;
    const int lane = t & 63;
    const int row = blockIdx.x * 4 + w;

    u32* hist  = hist_s[w];
    u16* candA = cand_s[w];
    u16* candB = cand_s[w] + CAPC;
    u32* cnt   = cnt_s[w];

    const uint4* rp = (const uint4*)(Cp + (size_t)row * NROW);

    // zero hist + counters (wave-private; DS pipe is in-order per wave)
    {
        const uint4 z = make_uint4(0, 0, 0, 0);
        *(uint4*)&hist[lane * 8]     = z;
        *(uint4*)&hist[lane * 8 + 4] = z;
        if (lane < 2) cnt[lane] = 0;
    }

    // exact fp32 l_pos
    float lp;
    {
        float4 q4 = *(const float4*)(fq + (size_t)row * NDIM + lane * 4);
        float4 k4 = *(const float4*)(fk + (size_t)row * NDIM + lane * 4);
        float p = q4.x * k4.x + q4.y * k4.y + q4.z * k4.z + q4.w * k4.w;
#pragma unroll
        for (int o = 32; o; o >>= 1) p += __shfl_down(p, o);
        lp = __shfl(p, 0);
    }

    // ---- pass 1: linear-bin histogram (compiler-scheduled loads) ----
#pragma unroll 4
    for (int i = 0; i < 16; ++i) {
        uint4 v = rp[i * 64 + lane];
        u32 ks[8] = { v.x & 0xFFFFu, v.x >> 16, v.y & 0xFFFFu, v.y >> 16,
                      v.z & 0xFFFFu, v.z >> 16, v.w & 0xFFFFu, v.w >> 16 };
#pragma unroll
        for (int q = 0; q < 8; ++q)
            atomicAdd(&hist[binOf(ks[q])], 1u);
    }

    // ---- wave-local suffix scan (8 bins/lane); locate boundary bins ----
    u32 h[8], Wa[8];
    {
        uint4 h0 = *(const uint4*)&hist[lane * 8];
        uint4 h1 = *(const uint4*)&hist[lane * 8 + 4];
        h[0] = h0.x; h[1] = h0.y; h[2] = h0.z; h[3] = h0.w;
        h[4] = h1.x; h[5] = h1.y; h[6] = h1.z; h[7] = h1.w;
    }
    Wa[7] = 0;
#pragma unroll
    for (int j = 6; j >= 0; --j) Wa[j] = Wa[j + 1] + h[j + 1];
    u32 P = Wa[0] + h[0];
    u32 s = P;
#pragma unroll
    for (int o = 1; o < 64; o <<= 1) {
        u32 vv = __shfl_down(s, o);
        if (lane + o < 64) s += vv;
    }
    const u32 Tex = s - P;     // keys in bins owned by higher lanes

    u32 fA = 0, pkA = 0, fB = 0, pkB = 0;
#pragma unroll
    for (int j = 0; j < 8; ++j) {
        u32 T = Tex + Wa[j];          // keys in bins strictly above this bin
        u32 e = T + h[j];
        if ((u32)K_BOT >= T && (u32)K_BOT < e)
            { fA = 1; pkA = ((u32)(lane * 8 + j) << 13) | ((u32)K_BOT - T); }
        if ((u32)(K_TOP - 1) >= T && (u32)(K_TOP - 1) < e)
            { fB = 1; pkB = ((u32)(lane * 8 + j) << 13) | ((u32)(K_TOP - 1) - T); }
    }
    {
        u64 mA = __ballot(fA != 0);
        pkA = __shfl(pkA, __ffsll((unsigned long long)mA) - 1);
        u64 mB = __ballot(fB != 0);
        pkB = __shfl(pkB, __ffsll((unsigned long long)mB) - 1);
    }
    const u32 binA = pkA >> 13, remA = pkA & 8191u;
    const u32 binB = pkB >> 13, remB = pkB & 8191u;
    const u32 TA = (u32)K_BOT - remA;
    const u32 TB = (u32)(K_TOP - 1) - remB;
    const u32 hA = hist[binA];
    const u32 hB = hist[binB];
    const bool same = (binA == binB);

    // ---- u16 key-space edges of binA / binB (exact preimage of binOf) ----
    // lane 0: kLo(binA), lane 1: kLo(binA+1), lane 2: kLo(binB), lane 3: kLo(binB+1)
    u32 kALo, kAHip1, kBLo, kBHip1;
    {
        const u32 tsel = (u32)(lane & 3);
        const u32 btgt = (tsel == 0) ? binA : (tsel == 1) ? binA + 1
                       : (tsel == 2) ? binB : binB + 1;
        u32 lo = 0, hi = 65536;
#pragma unroll 1
        for (int it = 0; it < 17; ++it) {
            if (lo < hi) {
                u32 mid = (lo + hi) >> 1;
                if ((u32)binOf(mid) >= btgt) hi = mid; else lo = mid + 1;
            }
        }
        kALo   = __shfl(lo, 0);
        kAHip1 = __shfl(lo, 1);
        kBLo   = __shfl(lo, 2);
        kBHip1 = __shfl(lo, 3);
    }

    u32 ua, ub, Ga, Ea, Gb;
    float m_, smLane;

    if (hA <= CAPC && hB <= CAPC) {
        // ---- fast path: pass 2 = integer-compare classify ----
        const float aUp = (float)(binA + 1) * (180.0f / (float)NBIN) - 90.0f;
        m_ = fmaxf(fmaxf(lp, aUp), -10.0f) * INV_T;   // >= true window max
        float sm = 0.f;
#pragma unroll 4
        for (int i = 0; i < 16; ++i) {
            uint4 v = rp[i * 64 + lane];
            u32 ks[8] = { v.x & 0xFFFFu, v.x >> 16, v.y & 0xFFFFu, v.y >> 16,
                          v.z & 0xFFFFu, v.z >> 16, v.w & 0xFFFFu, v.w >> 16 };
#pragma unroll
            for (int q = 0; q < 8; ++q) {
                u32 key = ks[q];
                if (key >= kALo && key < kAHip1) {          // bin == binA
                    u32 ix = atomicAdd(&cnt[0], 1u);
                    candA[ix] = (u16)key;
                } else if (key >= kBLo && key < kBHip1) {   // bin == binB
                    u32 ix = atomicAdd(&cnt[1], 1u);
                    candB[ix] = (u16)key;
                } else if (key >= kBHip1 && key < kALo) {   // strict mid-window
                    sm += __expf(unmap16(key) * INV_T - m_);
                }
            }
        }
        const u32 nA = hA;
        const u32 nB = same ? hA : hB;
        const u16* lB = same ? candA : candB;
        ua = bisect_list(candA, nA, remA, lane);
        ub = bisect_list(lB, nB, remB, lane);
        u32 gA, eA, gB, eB;
        count_list(candA, nA, ua, lane, &gA, &eA);
        count_list(lB, nB, ub, lane, &gB, &eB);
        Ga = TA + gA; Ea = eA; Gb = TB + gB;
        sm += sumwin_list(candA, nA, ua, ub, m_, lane);
        if (!same) sm += sumwin_list(candB, nB, ua, ub, m_, lane);
        smLane = sm;
    } else {
        // ---- fallback: exact full-row bisect (pathological data only) ----
        ua = bisect_row(rp, (u32)K_BOT, lane);
        ub = bisect_row(rp, (u32)(K_TOP - 1), lane);
        m_ = fmaxf(fmaxf(lp, unmap16(ua)), -10.0f) * INV_T;
        u32 cga = 0, cea = 0, cgb = 0;
        float sm = 0.f;
        for (int i = 0; i < 16; ++i) {
            uint4 v = rp[i * 64 + lane];
            u32 ks[8] = { v.x & 0xFFFFu, v.x >> 16, v.y & 0xFFFFu, v.y >> 16,
                          v.z & 0xFFFFu, v.z >> 16, v.w & 0xFFFFu, v.w >> 16 };
#pragma unroll
            for (int q = 0; q < 8; ++q) {
                u32 u = ks[q];
                cga += (u > ua); cea += (u == ua); cgb += (u > ub);
                if (u > ub && u < ua) sm += __expf(unmap16(u) * INV_T - m_);
            }
        }
        Ga = wave_sum_u32(cga); Ea = wave_sum_u32(cea); Gb = wave_sum_u32(cgb);
        smLane = sm;
    }

    // wave-reduce the exp partials
    float smT = smLane;
#pragma unroll
    for (int o = 32; o; o >>= 1) smT += __shfl_down(smT, o);

    if (lane == 0) {
        float a = unmap16(ua), bv = unmap16(ub);
        float expA = __expf(a * INV_T - m_);
        float tot;
        if (ua == ub) {
            tot = (float)N_SEL * expA;
        } else {
            float expB = __expf(bv * INV_T - m_);
            tot = smT + (float)(int)(Ga + Ea - (u32)K_BOT) * expA
                      + (float)(int)((u32)K_TOP - Gb) * expB;
        }
        tot += __expf(lp * INV_T - m_) + (float)N_UNSEL * __expf(-10.0f * INV_T - m_);
        loss[row] = m_ + __logf(tot) - lp * INV_T;
    }
}

// ---------------- host ----------------
extern "C" void kernel_launch(void* const* d_in, const int* in_sizes, int n_in,
                              void* d_out, int out_size, void* d_ws, size_t ws_size,
                              hipStream_t stream) {
    const float* fq = (const float*)d_in[0];
    const float* fk = (const float*)d_in[1];
    float* out = (float*)d_out;

    char* ws = (char*)d_ws;
    u16* keys = (u16*)ws;                                  // 128 MiB
    u16* qb = (u16*)(ws + (size_t)NROW * NROW * 2);        // 4 MiB
    u16* kb = qb + (size_t)NROW * NDIM;                    // 4 MiB

    cvt_bf16<<<4096, 256, 0, stream>>>(fq, fk, qb, kb);
    gemm_keys<<<dim3(NROW / 128, NROW / 128), 256, 0, stream>>>(qb, kb, keys);
    rank_lse<<<NROW / 4, 256, 0, stream>>>(keys, fq, fk, out);
}

// Round 11
// 155.358 us; speedup vs baseline: 1.0664x; 1.0162x over previous
//
#include <hip/hip_runtime.h>
#include <hip/hip_bf16.h>

#define NROW 8192
#define NDIM 256
#define INV_T (1.0f / 0.07f)
#define K_BOT 819      // first selected descending rank
#define K_TOP 4095     // one past last selected rank
#define N_SEL 3276
#define N_UNSEL 4916   // 8192 - N_SEL (includes diagonal at -10)

typedef unsigned int u32;
typedef unsigned short u16;
typedef short s16;
typedef unsigned long long u64;
typedef __bf16 bf16_t;
typedef s16 s16x8 __attribute__((ext_vector_type(8)));
typedef float f32x4 __attribute__((ext_vector_type(4)));

__device__ __forceinline__ u16 bfbits(float f) {
    return __builtin_bit_cast(u16, (bf16_t)f);   // RNE f32->bf16, raw bits
}
// order-preserving bf16-bits -> u16 key (bigger float <=> bigger key)
__device__ __forceinline__ u16 map16(u16 b) {
    return (b & 0x8000u) ? (u16)~b : (u16)(b | 0x8000u);
}
__device__ __forceinline__ float unmap16(u32 m) {
    u16 b = (m & 0x8000u) ? (u16)(m & 0x7FFFu) : (u16)~(u16)m;
    return __uint_as_float(((u32)b) << 16);
}

__device__ __forceinline__ void gload16(const void* g, void* l) {
    __builtin_amdgcn_global_load_lds(
        (const __attribute__((address_space(1))) u32*)g,
        (__attribute__((address_space(3))) u32*)l, 16, 0, 0);
}

// ---------------- fp32 -> bf16 (both inputs, one launch) ----------------
__global__ __launch_bounds__(256) void cvt_bf16(const float* __restrict__ in0,
                                                const float* __restrict__ in1,
                                                u16* __restrict__ out0,
                                                u16* __restrict__ out1) {
    int b = blockIdx.x;
    const float* in = (b < 2048) ? in0 : in1;
    u16* out = (b < 2048) ? out0 : out1;
    int i = ((b & 2047) * 256 + threadIdx.x) * 4;
    float4 v = *(const float4*)(in + i);
    ushort4 o;
    o.x = bfbits(v.x); o.y = bfbits(v.y); o.z = bfbits(v.z); o.w = bfbits(v.w);
    *(ushort4*)(out + i) = o;
}

// ---------------- GEMM: keys = map16(bf16(Q @ K^T)) ----------------
// (round-8 proven form; XCD swizzle reverted — measured -11 us)
__global__ __launch_bounds__(256) void gemm_keys(const u16* __restrict__ Qb,
                                                 const u16* __restrict__ Kb,
                                                 u16* __restrict__ Cp) {
    constexpr int BK = 64;
    __shared__ __align__(16) char smem[128 * 132 * 2];
    u16* sA = (u16*)smem;
    u16* sB = (u16*)(smem + 128 * BK * 2);
    u16* sC = (u16*)smem;

    const int tid  = threadIdx.x;
    const int lane = tid & 63;
    const int wid  = tid >> 6;
    const int wr = wid >> 1, wc = wid & 1;
    const int bm = blockIdx.y * 128;
    const int bn = blockIdx.x * 128;
    const int kg = lane >> 4;
    const int fr = lane & 15;
    const int srr = lane >> 3;
    const int srj = (lane & 7) ^ srr;

    f32x4 acc[4][4] = {};

    for (int k0 = 0; k0 < NDIM; k0 += BK) {
        __syncthreads();
#pragma unroll
        for (int s = 0; s < 4; ++s) {
            int seg = wid * 4 + s;
            int row = seg * 8 + srr;
            gload16(Qb + (size_t)(bm + row) * NDIM + k0 + srj * 8, &sA[seg * 512]);
            gload16(Kb + (size_t)(bn + row) * NDIM + k0 + srj * 8, &sB[seg * 512]);
        }
        __syncthreads();

#pragma unroll
        for (int kk = 0; kk < 2; ++kk) {
            s16x8 af[4], bfv[4];
#pragma unroll
            for (int m = 0; m < 4; ++m) {
                int row = wr * 64 + m * 16 + fr;
                int jp = (kk * 4 + kg) ^ (fr & 7);
                af[m] = *(const s16x8*)(&sA[row * BK + jp * 8]);
            }
#pragma unroll
            for (int n = 0; n < 4; ++n) {
                int row = wc * 64 + n * 16 + fr;
                int jp = (kk * 4 + kg) ^ (fr & 7);
                bfv[n] = *(const s16x8*)(&sB[row * BK + jp * 8]);
            }
#pragma unroll
            for (int m = 0; m < 4; ++m)
#pragma unroll
                for (int n = 0; n < 4; ++n)
                    acc[m][n] = __builtin_amdgcn_mfma_f32_16x16x32_bf16(
                        af[m], bfv[n], acc[m][n], 0, 0, 0);
        }
    }

    __syncthreads();
#pragma unroll
    for (int m = 0; m < 4; ++m)
#pragma unroll
        for (int n = 0; n < 4; ++n)
#pragma unroll
            for (int jj = 0; jj < 4; ++jj) {
                int r = wr * 64 + m * 16 + kg * 4 + jj;
                int c = wc * 64 + n * 16 + fr;
                sC[r * 132 + c] = map16(bfbits(acc[m][n][jj]));
            }
    __syncthreads();
    if (bm == bn) {
        if (tid < 128) sC[tid * 132 + tid] = 0;   // diagonal sentinel (unique min)
        __syncthreads();
    }
#pragma unroll
    for (int it = 0; it < 8; ++it) {
        int c = it * 256 + tid;
        int row = c >> 4, col8 = (c & 15) * 8;
        *(uint4*)(&Cp[(size_t)(bm + row) * NROW + bn + col8]) =
            *(const uint4*)(&sC[row * 132 + col8]);
    }
}

// ---------------- per-row rank select + LSE: 1 wave/row, 0 barriers --------
// Exact two-level integer key histogram: level 1 = key>>7 (512 bins, one per
// bf16 sign/exponent), level 2 = key&127 within the <=2 boundary bins.
// Unconditionally exact for any data; no cand lists, no fallback.
__global__ __launch_bounds__(256, 8) void rank_lse(const u16* __restrict__ Cp,
                                                   const float* __restrict__ fq,
                                                   const float* __restrict__ fk,
                                                   float* __restrict__ loss) {
    __shared__ u32 hist_s[4][512];   // 8 KB (per-wave private)
    __shared__ u32 sub_s[4][256];    // 4 KB (per-wave; A half [0,128), B [128,256))

    const int t = threadIdx.x;
    const int w = t >> 6;
    const int lane = t & 63;
    const int row = blockIdx.x * 4 + w;

    u32* hist = hist_s[w];
    u32* sub  = sub_s[w];
    const uint4* rp = (const uint4*)(Cp + (size_t)row * NROW);

    // zero LDS (wave-private; DS ops within a wave are in order)
    {
        const uint4 z = make_uint4(0, 0, 0, 0);
        *(uint4*)&hist[lane * 8]     = z;
        *(uint4*)&hist[lane * 8 + 4] = z;
        *(uint4*)&sub[lane * 4]      = z;
    }

    // exact fp32 l_pos
    float lp;
    {
        float4 q4 = *(const float4*)(fq + (size_t)row * NDIM + lane * 4);
        float4 k4 = *(const float4*)(fk + (size_t)row * NDIM + lane * 4);
        float p = q4.x * k4.x + q4.y * k4.y + q4.z * k4.z + q4.w * k4.w;
#pragma unroll
        for (int o = 32; o; o >>= 1) p += __shfl_down(p, o);
        lp = __shfl(p, 0);
    }

    // ---- S1: level-1 histogram, bin = key>>7 (pure integer) ----
#pragma unroll 4
    for (int i = 0; i < 16; ++i) {
        uint4 v = rp[i * 64 + lane];
        u32 ks[8] = { v.x & 0xFFFFu, v.x >> 16, v.y & 0xFFFFu, v.y >> 16,
                      v.z & 0xFFFFu, v.z >> 16, v.w & 0xFFFFu, v.w >> 16 };
#pragma unroll
        for (int q = 0; q < 8; ++q)
            atomicAdd(&hist[ks[q] >> 7], 1u);
    }

    // ---- suffix scan (8 bins/lane over 512); locate boundary bins ----
    u32 h[8], Wa[8];
    {
        uint4 h0 = *(const uint4*)&hist[lane * 8];
        uint4 h1 = *(const uint4*)&hist[lane * 8 + 4];
        h[0] = h0.x; h[1] = h0.y; h[2] = h0.z; h[3] = h0.w;
        h[4] = h1.x; h[5] = h1.y; h[6] = h1.z; h[7] = h1.w;
    }
    Wa[7] = 0;
#pragma unroll
    for (int j = 6; j >= 0; --j) Wa[j] = Wa[j + 1] + h[j + 1];
    u32 P = Wa[0] + h[0];
    u32 s = P;
#pragma unroll
    for (int o = 1; o < 64; o <<= 1) {
        u32 vv = __shfl_down(s, o);
        if (lane + o < 64) s += vv;
    }
    const u32 Tex = s - P;     // keys in bins owned by higher lanes

    u32 fA = 0, pkA = 0, fB = 0, pkB = 0;
#pragma unroll
    for (int j = 0; j < 8; ++j) {
        u32 T = Tex + Wa[j];          // keys in bins strictly above this bin
        u32 e = T + h[j];
        if ((u32)K_BOT >= T && (u32)K_BOT < e)
            { fA = 1; pkA = ((u32)(lane * 8 + j) << 13) | ((u32)K_BOT - T); }
        if ((u32)(K_TOP - 1) >= T && (u32)(K_TOP - 1) < e)
            { fB = 1; pkB = ((u32)(lane * 8 + j) << 13) | ((u32)(K_TOP - 1) - T); }
    }
    {
        u64 mA = __ballot(fA != 0);
        pkA = __shfl(pkA, __ffsll((unsigned long long)mA) - 1);
        u64 mB = __ballot(fB != 0);
        pkB = __shfl(pkB, __ffsll((unsigned long long)mB) - 1);
    }
    const u32 binA = pkA >> 13, remA = pkA & 8191u;
    const u32 binB = pkB >> 13, remB = pkB & 8191u;
    const u32 TA = (u32)K_BOT - remA;          // keys in bins above binA
    const u32 TB = (u32)(K_TOP - 1) - remB;    // keys in bins above binB
    const bool same = (binA == binB);

    // ---- S2: level-2 sub-histograms of the boundary bins (exact keys) ----
#pragma unroll 4
    for (int i = 0; i < 16; ++i) {
        uint4 v = rp[i * 64 + lane];
        u32 ks[8] = { v.x & 0xFFFFu, v.x >> 16, v.y & 0xFFFFu, v.y >> 16,
                      v.z & 0xFFFFu, v.z >> 16, v.w & 0xFFFFu, v.w >> 16 };
#pragma unroll
        for (int q = 0; q < 8; ++q) {
            u32 key = ks[q];
            u32 b = key >> 7;
            if (b == binA)       atomicAdd(&sub[key & 127u], 1u);
            else if (b == binB)  atomicAdd(&sub[128u + (key & 127u)], 1u);
        }
    }

    // ---- resolve exact boundary keys + tie counts from sub-hists ----
    u32 ua, Ga, Ea, ub, Gb, GbEq;
    {
        // half A
        u32 c0 = sub[lane * 2], c1 = sub[lane * 2 + 1];
        u32 s0 = c0 + c1, suf = s0;
#pragma unroll
        for (int o = 1; o < 64; o <<= 1) {
            u32 vv = __shfl_down(suf, o);
            if (lane + o < 64) suf += vv;
        }
        u32 TexL = suf - s0;
        u32 f = 0, pk = 0;
        u32 ab0 = TexL + c1;
        if (remA >= ab0 && remA < ab0 + c0) { f = 1; pk = ((u32)(lane * 2) << 16) | ab0; }
        if (remA >= TexL && remA < TexL + c1) { f = 1; pk = ((u32)(lane * 2 + 1) << 16) | TexL; }
        u64 mm = __ballot(f != 0);
        pk = __shfl(pk, __ffsll((unsigned long long)mm) - 1);
        u32 idx = pk >> 16, gt = pk & 0xFFFFu;
        ua = (binA << 7) | idx;
        Ga = TA + gt;
        Ea = sub[idx];
    }
    {
        const u32 base = same ? 0u : 128u;
        u32 c0 = sub[base + lane * 2], c1 = sub[base + lane * 2 + 1];
        u32 s0 = c0 + c1, suf = s0;
#pragma unroll
        for (int o = 1; o < 64; o <<= 1) {
            u32 vv = __shfl_down(suf, o);
            if (lane + o < 64) suf += vv;
        }
        u32 TexL = suf - s0;
        u32 f = 0, pk = 0;
        u32 ab0 = TexL + c1;
        if (remB >= ab0 && remB < ab0 + c0) { f = 1; pk = ((u32)(lane * 2) << 16) | ab0; }
        if (remB >= TexL && remB < TexL + c1) { f = 1; pk = ((u32)(lane * 2 + 1) << 16) | TexL; }
        u64 mm = __ballot(f != 0);
        pk = __shfl(pk, __ffsll((unsigned long long)mm) - 1);
        u32 idx = pk >> 16, gt = pk & 0xFFFFu;
        ub = (binB << 7) | idx;
        Gb = TB + gt;
        GbEq = 0; (void)GbEq;
    }

    // ---- S3: masked exp sweep over strict window (ub < key < ua) ----
    const float a = unmap16(ua);
    const float m_ = fmaxf(fmaxf(lp, a), -10.0f) * INV_T;   // exact max
    float sm = 0.f;
    if (ua != ub) {
        const u32 lo1 = ub + 1u, span = ua - ub - 1u;
#pragma unroll 4
        for (int i = 0; i < 16; ++i) {
            uint4 v = rp[i * 64 + lane];
            u32 ks[8] = { v.x & 0xFFFFu, v.x >> 16, v.y & 0xFFFFu, v.y >> 16,
                          v.z & 0xFFFFu, v.z >> 16, v.w & 0xFFFFu, v.w >> 16 };
#pragma unroll
            for (int q = 0; q < 8; ++q) {
                u32 key = ks[q];
                bool in = (key - lo1) < span;           // unsigned strict-between
                float e = __expf(unmap16(key) * INV_T - m_);
                sm += in ? e : 0.f;
            }
        }
    }
#pragma unroll
    for (int o = 32; o; o >>= 1) sm += __shfl_down(sm, o);

    if (lane == 0) {
        float bv = unmap16(ub);
        float expA = __expf(a * INV_T - m_);
        float tot;
        if (ua == ub) {
            tot = (float)N_SEL * expA;
        } else {
            float expB = __expf(bv * INV_T - m_);
            tot = sm + (float)(int)(Ga + Ea - (u32)K_BOT) * expA
                     + (float)(int)((u32)K_TOP - Gb) * expB;
        }
        tot += __expf(lp * INV_T - m_) + (float)N_UNSEL * __expf(-10.0f * INV_T - m_);
        loss[row] = m_ + __logf(tot) - lp * INV_T;
    }
}

// ---------------- host ----------------
extern "C" void kernel_launch(void* const* d_in, const int* in_sizes, int n_in,
                              void* d_out, int out_size, void* d_ws, size_t ws_size,
                              hipStream_t stream) {
    const float* fq = (const float*)d_in[0];
    const float* fk = (const float*)d_in[1];
    float* out = (float*)d_out;

    char* ws = (char*)d_ws;
    u16* keys = (u16*)ws;                                  // 128 MiB
    u16* qb = (u16*)(ws + (size_t)NROW * NROW * 2);        // 4 MiB
    u16* kb = qb + (size_t)NROW * NDIM;                    // 4 MiB

    cvt_bf16<<<4096, 256, 0, stream>>>(fq, fk, qb, kb);
    gemm_keys<<<dim3(NROW / 128, NROW / 128), 256, 0, stream>>>(qb, kb, keys);
    rank_lse<<<NROW / 4, 256, 0, stream>>>(keys, fq, fk, out);
}

// Round 12
// 130.177 us; speedup vs baseline: 1.2726x; 1.1934x over previous
//
#include <hip/hip_runtime.h>
#include <hip/hip_bf16.h>

#define NROW 8192
#define NDIM 256
#define INV_T (1.0f / 0.07f)
#define K_BOT 819      // first selected descending rank
#define K_TOP 4095     // one past last selected rank
#define N_SEL 3276
#define N_UNSEL 4916   // 8192 - N_SEL (includes diagonal at -10)

typedef unsigned int u32;
typedef unsigned short u16;
typedef short s16;
typedef unsigned long long u64;
typedef __bf16 bf16_t;
typedef s16 s16x8 __attribute__((ext_vector_type(8)));
typedef float f32x4 __attribute__((ext_vector_type(4)));

__device__ __forceinline__ u16 bfbits(float f) {
    return __builtin_bit_cast(u16, (bf16_t)f);   // RNE f32->bf16, raw bits
}
// order-preserving bf16-bits -> u16 key (bigger float <=> bigger key)
__device__ __forceinline__ u16 map16(u16 b) {
    return (b & 0x8000u) ? (u16)~b : (u16)(b | 0x8000u);
}
__device__ __forceinline__ float unmap16(u32 m) {
    u16 b = (m & 0x8000u) ? (u16)(m & 0x7FFFu) : (u16)~(u16)m;
    return __uint_as_float(((u32)b) << 16);
}

__device__ __forceinline__ void gload16(const void* g, void* l) {
    __builtin_amdgcn_global_load_lds(
        (const __attribute__((address_space(1))) u32*)g,
        (__attribute__((address_space(3))) u32*)l, 16, 0, 0);
}

// ---------------- fp32 -> bf16 (both inputs, one launch) ----------------
__global__ __launch_bounds__(256) void cvt_bf16(const float* __restrict__ in0,
                                                const float* __restrict__ in1,
                                                u16* __restrict__ out0,
                                                u16* __restrict__ out1) {
    int b = blockIdx.x;
    const float* in = (b < 2048) ? in0 : in1;
    u16* out = (b < 2048) ? out0 : out1;
    int i = ((b & 2047) * 256 + threadIdx.x) * 4;
    float4 v = *(const float4*)(in + i);
    ushort4 o;
    o.x = bfbits(v.x); o.y = bfbits(v.y); o.z = bfbits(v.z); o.w = bfbits(v.w);
    *(ushort4*)(out + i) = o;
}

// ---------------- GEMM: keys = map16(bf16(Q @ K^T)) ----------------
__global__ __launch_bounds__(256) void gemm_keys(const u16* __restrict__ Qb,
                                                 const u16* __restrict__ Kb,
                                                 u16* __restrict__ Cp) {
    constexpr int BK = 64;
    __shared__ __align__(16) char smem[128 * 132 * 2];
    u16* sA = (u16*)smem;
    u16* sB = (u16*)(smem + 128 * BK * 2);
    u16* sC = (u16*)smem;

    const int tid  = threadIdx.x;
    const int lane = tid & 63;
    const int wid  = tid >> 6;
    const int wr = wid >> 1, wc = wid & 1;
    const int bm = blockIdx.y * 128;
    const int bn = blockIdx.x * 128;
    const int kg = lane >> 4;
    const int fr = lane & 15;
    const int srr = lane >> 3;
    const int srj = (lane & 7) ^ srr;

    f32x4 acc[4][4] = {};

    for (int k0 = 0; k0 < NDIM; k0 += BK) {
        __syncthreads();
#pragma unroll
        for (int s = 0; s < 4; ++s) {
            int seg = wid * 4 + s;
            int row = seg * 8 + srr;
            gload16(Qb + (size_t)(bm + row) * NDIM + k0 + srj * 8, &sA[seg * 512]);
            gload16(Kb + (size_t)(bn + row) * NDIM + k0 + srj * 8, &sB[seg * 512]);
        }
        __syncthreads();

#pragma unroll
        for (int kk = 0; kk < 2; ++kk) {
            s16x8 af[4], bfv[4];
#pragma unroll
            for (int m = 0; m < 4; ++m) {
                int row = wr * 64 + m * 16 + fr;
                int jp = (kk * 4 + kg) ^ (fr & 7);
                af[m] = *(const s16x8*)(&sA[row * BK + jp * 8]);
            }
#pragma unroll
            for (int n = 0; n < 4; ++n) {
                int row = wc * 64 + n * 16 + fr;
                int jp = (kk * 4 + kg) ^ (fr & 7);
                bfv[n] = *(const s16x8*)(&sB[row * BK + jp * 8]);
            }
#pragma unroll
            for (int m = 0; m < 4; ++m)
#pragma unroll
                for (int n = 0; n < 4; ++n)
                    acc[m][n] = __builtin_amdgcn_mfma_f32_16x16x32_bf16(
                        af[m], bfv[n], acc[m][n], 0, 0, 0);
        }
    }

    __syncthreads();
#pragma unroll
    for (int m = 0; m < 4; ++m)
#pragma unroll
        for (int n = 0; n < 4; ++n)
#pragma unroll
            for (int jj = 0; jj < 4; ++jj) {
                int r = wr * 64 + m * 16 + kg * 4 + jj;
                int c = wc * 64 + n * 16 + fr;
                sC[r * 132 + c] = map16(bfbits(acc[m][n][jj]));
            }
    __syncthreads();
    if (bm == bn) {
        if (tid < 128) sC[tid * 132 + tid] = 0;   // diagonal sentinel (unique min)
        __syncthreads();
    }
#pragma unroll
    for (int it = 0; it < 8; ++it) {
        int c = it * 256 + tid;
        int row = c >> 4, col8 = (c & 15) * 8;
        *(uint4*)(&Cp[(size_t)(bm + row) * NROW + bn + col8]) =
            *(const uint4*)(&sC[row * 132 + col8]);
    }
}

// ---------------- rank select + LSE: 1 wave/row, 0 barriers, 2 sweeps -----
// resolve rank `rem` within a 128-key sub-hist (packed u16 counts, 64 words)
__device__ __forceinline__ void resolve_slot(const u32* sub, int slot, u32 rem,
                                             int lane, u32* idxOut, u32* gtOut) {
    u32 word = sub[slot * 64 + lane];
    u32 c0 = word & 0xFFFFu, c1 = word >> 16;     // idx 2*lane, 2*lane+1
    u32 s0 = c0 + c1, suf = s0;
#pragma unroll
    for (int o = 1; o < 64; o <<= 1) {
        u32 v = __shfl_down(suf, o);
        if (lane + o < 64) suf += v;
    }
    u32 TexL = suf - s0;                  // counts in higher lanes
    u32 f = 0, pk = 0;
    u32 ab0 = TexL + c1;                  // keys above idx 2*lane
    if (rem >= ab0 && rem < ab0 + c0) { f = 1; pk = ((u32)(lane * 2) << 16) | ab0; }
    if (rem >= TexL && rem < TexL + c1) { f = 1; pk = ((u32)(lane * 2 + 1) << 16) | TexL; }
    u64 mm = __ballot(f != 0);
    pk = __shfl(pk, (int)(__ffsll((unsigned long long)mm) - 1));
    *idxOut = pk >> 16;
    *gtOut = pk & 0xFFFFu;
}

__global__ __launch_bounds__(256, 8) void rank_lse(const u16* __restrict__ Cp,
                                                   const float* __restrict__ fq,
                                                   const float* __restrict__ fk,
                                                   float* __restrict__ loss) {
    __shared__ u32 lds_s[4][1152];        // 18.4 KB total; per-wave private
    const int t = threadIdx.x;
    const int w = t >> 6;
    const int lane = t & 63;
    const int row = blockIdx.x * 4 + w;

    u32* W  = lds_s[w];
    u32* h1 = W;                           // [0,512)    S1 hist copy 0
    u32* h2 = W + 520;                     // [520,1032) S1 hist copy 1 (bank-offset)
    u32* sub = W;                          // [0,512)    phase-2 sub-hists (alias h1)

    const uint4* rp = (const uint4*)(Cp + (size_t)row * NROW);

    // zero hist copies
    {
        const uint4 z = make_uint4(0, 0, 0, 0);
#pragma unroll
        for (int i = 0; i < 4; ++i) *(uint4*)&W[i * 256 + lane * 4] = z;
        *(uint2*)&W[1024 + lane * 2] = make_uint2(0, 0);
    }

    // exact fp32 l_pos
    float lp;
    {
        float4 q4 = *(const float4*)(fq + (size_t)row * NDIM + lane * 4);
        float4 k4 = *(const float4*)(fk + (size_t)row * NDIM + lane * 4);
        float p = q4.x * k4.x + q4.y * k4.y + q4.z * k4.z + q4.w * k4.w;
#pragma unroll
        for (int o = 32; o; o >>= 1) p += __shfl_down(p, o);
        lp = __shfl(p, 0);
    }

    // ---- S1: 512-bin hist (key>>7), 2-copy split by lane parity ----
    u32* const hb = (lane & 1) ? h2 : h1;
#pragma unroll 4
    for (int i = 0; i < 16; ++i) {
        uint4 v = rp[i * 64 + lane];
        u32 vv[4] = { v.x, v.y, v.z, v.w };
#pragma unroll
        for (int q = 0; q < 4; ++q) {
            atomicAdd(&hb[(vv[q] >> 7) & 0x1FFu], 1u);
            atomicAdd(&hb[vv[q] >> 23], 1u);
        }
    }

    // ---- suffix scan (8 bins/lane over 512); locate boundary bins ----
    u32 h[8], Wa[8];
    {
        uint4 a0 = *(const uint4*)&h1[lane * 8];
        uint4 a1 = *(const uint4*)&h1[lane * 8 + 4];
        uint4 b0 = *(const uint4*)&h2[lane * 8];
        uint4 b1 = *(const uint4*)&h2[lane * 8 + 4];
        h[0] = a0.x + b0.x; h[1] = a0.y + b0.y; h[2] = a0.z + b0.z; h[3] = a0.w + b0.w;
        h[4] = a1.x + b1.x; h[5] = a1.y + b1.y; h[6] = a1.z + b1.z; h[7] = a1.w + b1.w;
    }
    Wa[7] = 0;
#pragma unroll
    for (int j = 6; j >= 0; --j) Wa[j] = Wa[j + 1] + h[j + 1];
    u32 P = Wa[0] + h[0];
    u32 s = P;
#pragma unroll
    for (int o = 1; o < 64; o <<= 1) {
        u32 vv = __shfl_down(s, o);
        if (lane + o < 64) s += vv;
    }
    const u32 Tex = s - P;

    u32 fA = 0, pkA = 0, fB = 0, pkB = 0;
#pragma unroll
    for (int j = 0; j < 8; ++j) {
        u32 T = Tex + Wa[j];
        u32 e = T + h[j];
        if ((u32)K_BOT >= T && (u32)K_BOT < e)
            { fA = 1; pkA = ((u32)(lane * 8 + j) << 13) | ((u32)K_BOT - T); }
        if ((u32)(K_TOP - 1) >= T && (u32)(K_TOP - 1) < e)
            { fB = 1; pkB = ((u32)(lane * 8 + j) << 13) | ((u32)(K_TOP - 1) - T); }
    }
    {
        u64 mA = __ballot(fA != 0);
        pkA = __shfl(pkA, (int)(__ffsll((unsigned long long)mA) - 1));
        u64 mB = __ballot(fB != 0);
        pkB = __shfl(pkB, (int)(__ffsll((unsigned long long)mB) - 1));
    }
    const u32 binA = pkA >> 13, remA = pkA & 8191u;
    const u32 binB = pkB >> 13, remB = pkB & 8191u;
    const u32 TA = (u32)K_BOT - remA;
    const u32 TB = (u32)(K_TOP - 1) - remB;

    // ---- slot assignment (pure arithmetic) ----
    // slots: 0 = binB; 1..topSlots = bins [lo2 .. binA]. Cutoff: values more
    // than 2.8 below binA's lower edge contribute < e^-40 of the max term.
    const float edgeA = unmap16(binA << 7);
    int lo2, topSlots;
    bool fb = false;
    if (edgeA > -1e37f && edgeA < 1e37f) {
        float vt = edgeA - 2.8f;
        int vtBin = (int)((u32)map16(bfbits(vt)) >> 7);
        int binLoSafe = vtBin - 1; if (binLoSafe < 0) binLoSafe = 0;
        int m = (binLoSafe < (int)binA) ? binLoSafe : (int)binA;
        lo2 = ((int)binB + 1 > m) ? (int)binB + 1 : m;
        topSlots = ((int)binA >= lo2) ? ((int)binA - lo2 + 1) : 0;
        if (topSlots + 1 > 8) fb = true;
    } else {
        fb = true;
    }
    if (fb) {                       // fallback: slots only for binB, binA
        lo2 = (int)binA;
        topSlots = ((int)binA > (int)binB) ? 1 : 0;
    }
    const int nslot = topSlots + 1;
    const int sA = topSlots;        // slot of binA (0 when binA==binB)

    // ---- zero sub region, then S2: sub-hist sweep (packed u16 counts) ----
    {
        const uint4 z = make_uint4(0, 0, 0, 0);
#pragma unroll
        for (int i = 0; i < 2; ++i) *(uint4*)&sub[i * 256 + lane * 4] = z;
    }
#pragma unroll 4
    for (int i = 0; i < 16; ++i) {
        uint4 v = rp[i * 64 + lane];
        u32 vv[4] = { v.x, v.y, v.z, v.w };
#pragma unroll
        for (int q = 0; q < 4; ++q) {
#pragma unroll
            for (int hh = 0; hh < 2; ++hh) {
                u32 key = hh ? (vv[q] >> 16) : (vv[q] & 0xFFFFu);
                u32 b = key >> 7;
                int sl = (b == binB) ? 0
                       : (((u32)((int)b - lo2) < (u32)topSlots) ? ((int)b - lo2 + 1) : -1);
                if (sl >= 0)
                    atomicAdd(&sub[sl * 64 + ((key & 127u) >> 1)],
                              (key & 1u) ? 0x10000u : 1u);
            }
        }
    }

    // ---- resolve exact boundary keys + tie counts ----
    u32 idxA, gtA, idxB, gtB;
    resolve_slot(sub, sA, remA, lane, &idxA, &gtA);
    resolve_slot(sub, 0,  remB, lane, &idxB, &gtB);
    const u32 ua = (binA << 7) | idxA;
    const u32 ub = (binB << 7) | idxB;
    const u32 Ga = TA + gtA;
    const u32 Gb = TB + gtB;
    u32 Ea;
    {
        u32 wv = sub[sA * 64 + (idxA >> 1)];
        Ea = (idxA & 1u) ? (wv >> 16) : (wv & 0xFFFFu);
    }

    const float a  = unmap16(ua);
    const float m_ = fmaxf(fmaxf(lp, a), -10.0f) * INV_T;   // exact max

    // ---- window sum ----
    float sm = 0.f;
    if (!fb) {
        for (int ss = 0; ss < nslot; ++ss) {          // wave-uniform
            u32 bs = (ss == 0) ? binB : (u32)(lo2 + ss - 1);
            u32 wv = sub[ss * 64 + lane];
            u32 c0 = wv & 0xFFFFu, c1 = wv >> 16;
            u32 k0 = (bs << 7) | (u32)(lane * 2);
            u32 k1 = k0 | 1u;
            if (c0 && k0 > ub && k0 < ua)
                sm += (float)c0 * __expf(unmap16(k0) * INV_T - m_);
            if (c1 && k1 > ub && k1 < ua)
                sm += (float)c1 * __expf(unmap16(k1) * INV_T - m_);
        }
    } else if (ua != ub) {
        // rare fallback: one extra full sweep with exact m_
        const u32 lo1 = ub + 1u, span = ua - ub - 1u;
#pragma unroll 4
        for (int i = 0; i < 16; ++i) {
            uint4 v = rp[i * 64 + lane];
            u32 vv[4] = { v.x, v.y, v.z, v.w };
#pragma unroll
            for (int q = 0; q < 4; ++q) {
#pragma unroll
                for (int hh = 0; hh < 2; ++hh) {
                    u32 key = hh ? (vv[q] >> 16) : (vv[q] & 0xFFFFu);
                    bool in = (key - lo1) < span;
                    float e = __expf(unmap16(key) * INV_T - m_);
                    sm += in ? e : 0.f;
                }
            }
        }
    }
#pragma unroll
    for (int o = 32; o; o >>= 1) sm += __shfl_down(sm, o);

    if (lane == 0) {
        float bv = unmap16(ub);
        float expA = __expf(a * INV_T - m_);
        float tot;
        if (ua == ub) {
            tot = (float)N_SEL * expA;
        } else {
            float expB = __expf(bv * INV_T - m_);
            tot = sm + (float)(int)(Ga + Ea - (u32)K_BOT) * expA
                     + (float)(int)((u32)K_TOP - Gb) * expB;
        }
        tot += __expf(lp * INV_T - m_) + (float)N_UNSEL * __expf(-10.0f * INV_T - m_);
        loss[row] = m_ + __logf(tot) - lp * INV_T;
    }
}

// ---------------- host ----------------
extern "C" void kernel_launch(void* const* d_in, const int* in_sizes, int n_in,
                              void* d_out, int out_size, void* d_ws, size_t ws_size,
                              hipStream_t stream) {
    const float* fq = (const float*)d_in[0];
    const float* fk = (const float*)d_in[1];
    float* out = (float*)d_out;

    char* ws = (char*)d_ws;
    u16* keys = (u16*)ws;                                  // 128 MiB
    u16* qb = (u16*)(ws + (size_t)NROW * NROW * 2);        // 4 MiB
    u16* kb = qb + (size_t)NROW * NDIM;                    // 4 MiB

    cvt_bf16<<<4096, 256, 0, stream>>>(fq, fk, qb, kb);
    gemm_keys<<<dim3(NROW / 128, NROW / 128), 256, 0, stream>>>(qb, kb, keys);
    rank_lse<<<NROW / 4, 256, 0, stream>>>(keys, fq, fk, out);
}